// Round 1
// baseline (447.006 us; speedup 1.0000x reference)
//
#include <hip/hip_runtime.h>
#include <hip/hip_bf16.h>

typedef __bf16 bf16_t;
typedef bf16_t bf16x8 __attribute__((ext_vector_type(8)));
typedef float f32x4 __attribute__((ext_vector_type(4)));

static __device__ __forceinline__ f32x4 mfma16(bf16x8 a, bf16x8 b, f32x4 c) {
  return __builtin_amdgcn_mfma_f32_16x16x32_bf16(a, b, c, 0, 0, 0);
}

static __device__ __forceinline__ void gload_lds16(const bf16_t* g, bf16_t* l) {
  __builtin_amdgcn_global_load_lds(
      (const __attribute__((address_space(1))) void*)g,
      (__attribute__((address_space(3))) void*)l, 16, 0, 0);
}

// ---------------------------------------------------------------- tiny kernels

__global__ __launch_bounds__(64) void lam_kernel(const float* __restrict__ lq1,
                                                 const float* __restrict__ lk1,
                                                 const float* __restrict__ lq2,
                                                 const float* __restrict__ lk2,
                                                 float* __restrict__ lamp) {
  int l = threadIdx.x;
  float a = lq1[l] * lk1[l];
  float b = lq2[l] * lk2[l];
  #pragma unroll
  for (int msk = 32; msk; msk >>= 1) {
    a += __shfl_xor(a, msk);
    b += __shfl_xor(b, msk);
  }
  if (l == 0) lamp[0] = __expf(a) - __expf(b) + 0.8f;
}

__global__ __launch_bounds__(256) void cvt_x_kernel(const float* __restrict__ x,
                                                    bf16_t* __restrict__ xb) {
  int i = (blockIdx.x * 256 + threadIdx.x) * 4;
  float4 v = *reinterpret_cast<const float4*>(x + i);
  union { bf16_t h[4]; uint2 u; } pk;
  pk.h[0] = (bf16_t)v.x; pk.h[1] = (bf16_t)v.y;
  pk.h[2] = (bf16_t)v.z; pk.h[3] = (bf16_t)v.w;
  *reinterpret_cast<uint2*>(xb + i) = pk.u;
}

// W: [K][N] fp32 row-major  ->  Wt: [N][K] bf16 row-major
__global__ __launch_bounds__(256) void transpose_cvt(const float* __restrict__ W,
                                                     bf16_t* __restrict__ Wt,
                                                     int K, int N) {
  __shared__ float tile[32][33];
  int n0 = blockIdx.x * 32, k0 = blockIdx.y * 32;
  int x = threadIdx.x, y = threadIdx.y;  // 32 x 8
  #pragma unroll
  for (int i = 0; i < 32; i += 8)
    tile[y + i][x] = W[(size_t)(k0 + y + i) * N + n0 + x];
  __syncthreads();
  #pragma unroll
  for (int i = 0; i < 32; i += 8)
    Wt[(size_t)(n0 + y + i) * K + k0 + x] = (bf16_t)tile[x][y + i];
}

// ---------------------------------------------------------------- GEMM (A[M][K] x Bt[N][K]^T)

template <typename OutT>
static __device__ __forceinline__ void gemm_bt_body(const bf16_t* __restrict__ A,
                                                    const bf16_t* __restrict__ Bt,
                                                    OutT* __restrict__ C,
                                                    int M, int N, int K) {
  __shared__ bf16_t As[128 * 32];
  __shared__ bf16_t Bs[128 * 32];
  const int tid = threadIdx.x;
  const int w = tid >> 6, lane = tid & 63;
  const int g = lane >> 4, l15 = lane & 15;
  const int wm = w >> 1, wn = w & 1;
  const int rowBase = blockIdx.y * 128, colBase = blockIdx.x * 128;

  // staging geometry: chunk = 1024B = 16 rows x 32 elems; wave w owns chunks 2w, 2w+1
  const int c0 = 2 * w, c1 = 2 * w + 1;
  const int srow0 = 16 * c0 + (lane >> 2);
  const int srow1 = 16 * c1 + (lane >> 2);
  const int scol = (lane & 3) * 8;

  f32x4 acc[4][4] = {};

  for (int k0 = 0; k0 < K; k0 += 32) {
    __syncthreads();  // prior compute done before overwrite
    gload_lds16(A + (size_t)(rowBase + srow0) * K + k0 + scol, &As[c0 * 512]);
    gload_lds16(A + (size_t)(rowBase + srow1) * K + k0 + scol, &As[c1 * 512]);
    gload_lds16(Bt + (size_t)(colBase + srow0) * K + k0 + scol, &Bs[c0 * 512]);
    gload_lds16(Bt + (size_t)(colBase + srow1) * K + k0 + scol, &Bs[c1 * 512]);
    __syncthreads();  // staging visible (implies vmcnt(0))

    bf16x8 bfr[4];
    #pragma unroll
    for (int j = 0; j < 4; ++j)
      bfr[j] = *reinterpret_cast<const bf16x8*>(&Bs[(wn * 64 + j * 16 + l15) * 32 + g * 8]);
    #pragma unroll
    for (int i = 0; i < 4; ++i) {
      bf16x8 afr = *reinterpret_cast<const bf16x8*>(&As[(wm * 64 + i * 16 + l15) * 32 + g * 8]);
      #pragma unroll
      for (int j = 0; j < 4; ++j)
        acc[i][j] = mfma16(afr, bfr[j], acc[i][j]);
    }
  }

  #pragma unroll
  for (int i = 0; i < 4; ++i) {
    #pragma unroll
    for (int j = 0; j < 4; ++j) {
      int row = rowBase + wm * 64 + i * 16 + 4 * g;
      int col = colBase + wn * 64 + j * 16 + l15;
      #pragma unroll
      for (int r = 0; r < 4; ++r)
        C[(size_t)(row + r) * N + col] = (OutT)acc[i][j][r];
    }
  }
}

__global__ __launch_bounds__(256) void gemm_qkv(const bf16_t* __restrict__ xb,
                                                const bf16_t* __restrict__ Wqt,
                                                const bf16_t* __restrict__ Wkt,
                                                const bf16_t* __restrict__ Wvt,
                                                bf16_t* __restrict__ Q,
                                                bf16_t* __restrict__ K,
                                                bf16_t* __restrict__ V) {
  const bf16_t* Bt = (blockIdx.z == 0) ? Wqt : (blockIdx.z == 1) ? Wkt : Wvt;
  bf16_t* C = (blockIdx.z == 0) ? Q : (blockIdx.z == 1) ? K : V;
  gemm_bt_body<bf16_t>(xb, Bt, C, 4096, 2048, 1024);
}

__global__ __launch_bounds__(256) void gemm_out(const bf16_t* __restrict__ Ob,
                                                const bf16_t* __restrict__ Wot,
                                                float* __restrict__ out) {
  gemm_bt_body<float>(Ob, Wot, out, 4096, 1024, 1024);
}

// ---------------------------------------------------------------- attention
// grid: (32 q-tiles, 32 b*h), 256 threads (4 waves), QT=KT=64, both components fused.
// Q/K/V global layout: [b*2048 + s][2048] with col = comp*1024 + h*64 + d.

__global__ __launch_bounds__(256)
void attn_kernel(const bf16_t* __restrict__ Qg, const bf16_t* __restrict__ Kg,
                 const bf16_t* __restrict__ Vg, bf16_t* __restrict__ Og,
                 const float* __restrict__ lamp) {
  __shared__ bf16_t Ks[2][64 * 72];  // padded rows: stride 72 elems (144B) -> conflict-free b128 reads
  __shared__ bf16_t Vt[2][64 * 72];  // transposed: [d][key], padded
  __shared__ bf16_t Ps[4][16 * 72];  // per-wave P, padded

  const int tid = threadIdx.x;
  const int w = tid >> 6, lane = tid & 63;
  const int g = lane >> 4, l15 = lane & 15;
  const int qt = blockIdx.x;
  const int b = blockIdx.y >> 4, h = blockIdx.y & 15;
  const int q0 = qt * 64;
  const int rowB = b * 2048;
  const float lam = *lamp;

  // stage 64x64 bf16 tiles of Q-or-K (both comps) into Ks, padded stride 72
  auto stageQK = [&](const bf16_t* __restrict__ src, int row0) {
    #pragma unroll
    for (int i = 0; i < 2; ++i) {
      int id = tid + 256 * i;       // 512 16B-chunks per comp
      int key = id >> 3, c = id & 7;
      size_t gofs = (size_t)(row0 + key) * 2048 + h * 64 + c * 8;
      #pragma unroll
      for (int comp = 0; comp < 2; ++comp) {
        uint4 v = *reinterpret_cast<const uint4*>(src + gofs + comp * 1024);
        *reinterpret_cast<uint4*>(&Ks[comp][key * 72 + c * 8]) = v;
      }
    }
  };
  // stage V transposed: wave -> (comp = w>>1, half = w&1), lane = key
  auto stageV = [&](int row0) {
    int comp = w >> 1, half = w & 1;
    int key = lane;
    size_t gofs = (size_t)(row0 + key) * 2048 + comp * 1024 + h * 64 + half * 32;
    #pragma unroll
    for (int c = 0; c < 4; ++c) {
      uint4 v = *reinterpret_cast<const uint4*>(Vg + gofs + c * 8);
      const bf16_t* e = reinterpret_cast<const bf16_t*>(&v);
      int d0 = half * 32 + c * 8;
      #pragma unroll
      for (int j = 0; j < 8; ++j)
        Vt[comp][(d0 + j) * 72 + key] = e[j];
    }
  };

  // ---- hoist Q fragments (wave w owns queries q0 + w*16 .. +15)
  stageQK(Qg, rowB + q0);
  __syncthreads();
  bf16x8 qf[2][2];
  #pragma unroll
  for (int comp = 0; comp < 2; ++comp)
    #pragma unroll
    for (int ks = 0; ks < 2; ++ks)
      qf[comp][ks] = *reinterpret_cast<const bf16x8*>(
          &Ks[comp][(w * 16 + l15) * 72 + ks * 32 + g * 8]);
  __syncthreads();

  f32x4 o[2][4] = {};
  float mrow[2][4], lrow[2][4];
  #pragma unroll
  for (int comp = 0; comp < 2; ++comp)
    #pragma unroll
    for (int r = 0; r < 4; ++r) { mrow[comp][r] = -1e30f; lrow[comp][r] = 0.f; }

  for (int j0 = 0; j0 <= q0; j0 += 64) {
    stageQK(Kg, rowB + j0);
    stageV(rowB + j0);
    __syncthreads();
    const bool diag = (j0 == q0);

    #pragma unroll
    for (int comp = 0; comp < 2; ++comp) {
      // ---- S = Q K^T   (C layout: key = l15, query = 4g + r)
      f32x4 s[4];
      #pragma unroll
      for (int n = 0; n < 4; ++n) {
        bf16x8 kf0 = *reinterpret_cast<const bf16x8*>(&Ks[comp][(n * 16 + l15) * 72 + 0 + g * 8]);
        bf16x8 kf1 = *reinterpret_cast<const bf16x8*>(&Ks[comp][(n * 16 + l15) * 72 + 32 + g * 8]);
        f32x4 z = {0.f, 0.f, 0.f, 0.f};
        z = mfma16(qf[comp][0], kf0, z);
        z = mfma16(qf[comp][1], kf1, z);
        s[n] = z;
      }
      // ---- scale + causal mask + row max
      float p[4][4];
      float rmax[4] = {-1e30f, -1e30f, -1e30f, -1e30f};
      #pragma unroll
      for (int n = 0; n < 4; ++n)
        #pragma unroll
        for (int r = 0; r < 4; ++r) {
          float sv = s[n][r] * 0.125f;
          if (diag) {
            int keyg = j0 + n * 16 + l15;
            int qg = q0 + w * 16 + 4 * g + r;
            if (keyg > qg) sv = -1e30f;
          }
          p[n][r] = sv;
          rmax[r] = fmaxf(rmax[r], sv);
        }
      #pragma unroll
      for (int msk = 1; msk <= 8; msk <<= 1)
        #pragma unroll
        for (int r = 0; r < 4; ++r)
          rmax[r] = fmaxf(rmax[r], __shfl_xor(rmax[r], msk));
      // ---- online softmax update
      float corr[4], rs[4];
      #pragma unroll
      for (int r = 0; r < 4; ++r) {
        float mn = fmaxf(mrow[comp][r], rmax[r]);
        corr[r] = __expf(mrow[comp][r] - mn);
        mrow[comp][r] = mn;
        rs[r] = 0.f;
      }
      #pragma unroll
      for (int n = 0; n < 4; ++n)
        #pragma unroll
        for (int r = 0; r < 4; ++r) {
          float pv = __expf(p[n][r] - mrow[comp][r]);
          p[n][r] = pv;
          rs[r] += pv;
        }
      #pragma unroll
      for (int msk = 1; msk <= 8; msk <<= 1)
        #pragma unroll
        for (int r = 0; r < 4; ++r)
          rs[r] += __shfl_xor(rs[r], msk);
      #pragma unroll
      for (int r = 0; r < 4; ++r)
        lrow[comp][r] = lrow[comp][r] * corr[r] + rs[r];
      #pragma unroll
      for (int nd = 0; nd < 4; ++nd)
        #pragma unroll
        for (int r = 0; r < 4; ++r)
          o[comp][nd][r] *= corr[r];
      // ---- P -> LDS (per-wave region; same-wave RAW ordered by compiler)
      #pragma unroll
      for (int n = 0; n < 4; ++n)
        #pragma unroll
        for (int r = 0; r < 4; ++r)
          Ps[w][(4 * g + r) * 72 + n * 16 + l15] = (bf16_t)p[n][r];
      // ---- O += P V   (A = P: row=query=l15, k=key; B = Vt: col=d=l15, k=key)
      #pragma unroll
      for (int ks = 0; ks < 2; ++ks) {
        bf16x8 pa = *reinterpret_cast<const bf16x8*>(&Ps[w][l15 * 72 + ks * 32 + g * 8]);
        #pragma unroll
        for (int nd = 0; nd < 4; ++nd) {
          bf16x8 vb = *reinterpret_cast<const bf16x8*>(
              &Vt[comp][(nd * 16 + l15) * 72 + ks * 32 + g * 8]);
          o[comp][nd] = mfma16(pa, vb, o[comp][nd]);
        }
      }
    }
    __syncthreads();  // all waves done with Ks/Vt before next stage
  }

  // ---- epilogue: (o1/l1 - lam*o2/l2) * 0.2 -> Og [4096][1024] bf16
  #pragma unroll
  for (int r = 0; r < 4; ++r) {
    float i1 = 1.f / lrow[0][r];
    float i2 = lam / lrow[1][r];
    int row = rowB + q0 + w * 16 + 4 * g + r;
    #pragma unroll
    for (int nd = 0; nd < 4; ++nd) {
      float val = (o[0][nd][r] * i1 - o[1][nd][r] * i2) * 0.2f;
      Og[(size_t)row * 1024 + h * 64 + nd * 16 + l15] = (bf16_t)val;
    }
  }
}

// ---------------------------------------------------------------- launch

extern "C" void kernel_launch(void* const* d_in, const int* in_sizes, int n_in,
                              void* d_out, int out_size, void* d_ws, size_t ws_size,
                              hipStream_t stream) {
  const float* x   = (const float*)d_in[0];
  const float* Wq  = (const float*)d_in[1];
  const float* Wk  = (const float*)d_in[2];
  const float* Wv  = (const float*)d_in[3];
  const float* Wo  = (const float*)d_in[4];
  const float* lq1 = (const float*)d_in[5];
  const float* lk1 = (const float*)d_in[6];
  const float* lq2 = (const float*)d_in[7];
  const float* lk2 = (const float*)d_in[8];
  float* out = (float*)d_out;

  char* ws = (char*)d_ws;
  size_t off = 0;
  auto alloc = [&](size_t bytes) -> char* {
    char* p = ws + off;
    off += (bytes + 255) & ~(size_t)255;
    return p;
  };
  bf16_t* xb  = (bf16_t*)alloc((size_t)4096 * 1024 * 2);
  bf16_t* Wqt = (bf16_t*)alloc((size_t)2048 * 1024 * 2);
  bf16_t* Wkt = (bf16_t*)alloc((size_t)2048 * 1024 * 2);
  bf16_t* Wvt = (bf16_t*)alloc((size_t)2048 * 1024 * 2);
  bf16_t* Wot = (bf16_t*)alloc((size_t)1024 * 1024 * 2);
  bf16_t* Qb  = (bf16_t*)alloc((size_t)4096 * 2048 * 2);
  bf16_t* Kb  = (bf16_t*)alloc((size_t)4096 * 2048 * 2);
  bf16_t* Vb  = (bf16_t*)alloc((size_t)4096 * 2048 * 2);
  bf16_t* Ob  = (bf16_t*)alloc((size_t)4096 * 1024 * 2);
  float*  lamp = (float*)alloc(256);

  lam_kernel<<<1, 64, 0, stream>>>(lq1, lk1, lq2, lk2, lamp);
  cvt_x_kernel<<<4096, 256, 0, stream>>>(x, xb);
  transpose_cvt<<<dim3(64, 32), dim3(32, 8), 0, stream>>>(Wq, Wqt, 1024, 2048);
  transpose_cvt<<<dim3(64, 32), dim3(32, 8), 0, stream>>>(Wk, Wkt, 1024, 2048);
  transpose_cvt<<<dim3(64, 32), dim3(32, 8), 0, stream>>>(Wv, Wvt, 1024, 2048);
  transpose_cvt<<<dim3(32, 32), dim3(32, 8), 0, stream>>>(Wo, Wot, 1024, 1024);
  gemm_qkv<<<dim3(16, 32, 3), 256, 0, stream>>>(xb, Wqt, Wkt, Wvt, Qb, Kb, Vb);
  attn_kernel<<<dim3(32, 32), 256, 0, stream>>>(Qb, Kb, Vb, Ob, lamp);
  gemm_out<<<dim3(8, 32), 256, 0, stream>>>(Ob, Wot, out);
}

// Round 2
// 260.093 us; speedup vs baseline: 1.7186x; 1.7186x over previous
//
#include <hip/hip_runtime.h>
#include <hip/hip_bf16.h>

typedef __bf16 bf16_t;
typedef bf16_t bf16x8 __attribute__((ext_vector_type(8)));
typedef float f32x4 __attribute__((ext_vector_type(4)));

static __device__ __forceinline__ f32x4 mfma16(bf16x8 a, bf16x8 b, f32x4 c) {
  return __builtin_amdgcn_mfma_f32_16x16x32_bf16(a, b, c, 0, 0, 0);
}

static __device__ __forceinline__ void gload_lds16(const bf16_t* g, bf16_t* l) {
  __builtin_amdgcn_global_load_lds(
      (const __attribute__((address_space(1))) void*)g,
      (__attribute__((address_space(3))) void*)l, 16, 0, 0);
}

// ---------------------------------------------------------------- tiny kernels

__global__ __launch_bounds__(64) void lam_kernel(const float* __restrict__ lq1,
                                                 const float* __restrict__ lk1,
                                                 const float* __restrict__ lq2,
                                                 const float* __restrict__ lk2,
                                                 float* __restrict__ lamp) {
  int l = threadIdx.x;
  float a = lq1[l] * lk1[l];
  float b = lq2[l] * lk2[l];
  #pragma unroll
  for (int msk = 32; msk; msk >>= 1) {
    a += __shfl_xor(a, msk);
    b += __shfl_xor(b, msk);
  }
  if (l == 0) lamp[0] = __expf(a) - __expf(b) + 0.8f;
}

__global__ __launch_bounds__(256) void cvt_x_kernel(const float* __restrict__ x,
                                                    bf16_t* __restrict__ xb) {
  int i = (blockIdx.x * 256 + threadIdx.x) * 4;
  float4 v = *reinterpret_cast<const float4*>(x + i);
  union { bf16_t h[4]; uint2 u; } pk;
  pk.h[0] = (bf16_t)v.x; pk.h[1] = (bf16_t)v.y;
  pk.h[2] = (bf16_t)v.z; pk.h[3] = (bf16_t)v.w;
  *reinterpret_cast<uint2*>(xb + i) = pk.u;
}

// W: [K][N] fp32 row-major  ->  Wt: [N][K] bf16 row-major
__global__ __launch_bounds__(256) void transpose_cvt(const float* __restrict__ W,
                                                     bf16_t* __restrict__ Wt,
                                                     int K, int N) {
  __shared__ float tile[32][33];
  int n0 = blockIdx.x * 32, k0 = blockIdx.y * 32;
  int x = threadIdx.x, y = threadIdx.y;  // 32 x 8
  #pragma unroll
  for (int i = 0; i < 32; i += 8)
    tile[y + i][x] = W[(size_t)(k0 + y + i) * N + n0 + x];
  __syncthreads();
  #pragma unroll
  for (int i = 0; i < 32; i += 8)
    Wt[(size_t)(n0 + y + i) * K + k0 + x] = (bf16_t)tile[x][y + i];
}

// ---------------------------------------------------------------- GEMM (A[M][K] x Bt[N][K]^T)
// vtrans: write C transposed as Ct[b][col][s] with row = b*2048+s (for V).

template <typename OutT>
static __device__ __forceinline__ void gemm_bt_body(const bf16_t* __restrict__ A,
                                                    const bf16_t* __restrict__ Bt,
                                                    OutT* __restrict__ C,
                                                    int M, int N, int K,
                                                    bool vtrans) {
  __shared__ bf16_t As[128 * 32];
  __shared__ bf16_t Bs[128 * 32];
  const int tid = threadIdx.x;
  const int w = tid >> 6, lane = tid & 63;
  const int g = lane >> 4, l15 = lane & 15;
  const int wm = w >> 1, wn = w & 1;
  const int rowBase = blockIdx.y * 128, colBase = blockIdx.x * 128;

  const int c0 = 2 * w, c1 = 2 * w + 1;
  const int srow0 = 16 * c0 + (lane >> 2);
  const int srow1 = 16 * c1 + (lane >> 2);
  const int scol = (lane & 3) * 8;

  f32x4 acc[4][4] = {};

  for (int k0 = 0; k0 < K; k0 += 32) {
    __syncthreads();
    gload_lds16(A + (size_t)(rowBase + srow0) * K + k0 + scol, &As[c0 * 512]);
    gload_lds16(A + (size_t)(rowBase + srow1) * K + k0 + scol, &As[c1 * 512]);
    gload_lds16(Bt + (size_t)(colBase + srow0) * K + k0 + scol, &Bs[c0 * 512]);
    gload_lds16(Bt + (size_t)(colBase + srow1) * K + k0 + scol, &Bs[c1 * 512]);
    __syncthreads();

    bf16x8 bfr[4];
    #pragma unroll
    for (int j = 0; j < 4; ++j)
      bfr[j] = *reinterpret_cast<const bf16x8*>(&Bs[(wn * 64 + j * 16 + l15) * 32 + g * 8]);
    #pragma unroll
    for (int i = 0; i < 4; ++i) {
      bf16x8 afr = *reinterpret_cast<const bf16x8*>(&As[(wm * 64 + i * 16 + l15) * 32 + g * 8]);
      #pragma unroll
      for (int j = 0; j < 4; ++j)
        acc[i][j] = mfma16(afr, bfr[j], acc[i][j]);
    }
  }

  if (vtrans) {
    #pragma unroll
    for (int i = 0; i < 4; ++i) {
      #pragma unroll
      for (int j = 0; j < 4; ++j) {
        int row = rowBase + wm * 64 + i * 16 + 4 * g;  // global s in [0,4096)
        int col = colBase + wn * 64 + j * 16 + l15;    // [0,2048)
        int bb = row >> 11, s = row & 2047;
        union { bf16_t h[4]; uint2 u; } pk;
        #pragma unroll
        for (int r = 0; r < 4; ++r) pk.h[r] = (bf16_t)acc[i][j][r];
        *reinterpret_cast<uint2*>(
            (bf16_t*)C + ((size_t)bb * 2048 + col) * 2048 + s) = pk.u;
      }
    }
  } else {
    #pragma unroll
    for (int i = 0; i < 4; ++i) {
      #pragma unroll
      for (int j = 0; j < 4; ++j) {
        int row = rowBase + wm * 64 + i * 16 + 4 * g;
        int col = colBase + wn * 64 + j * 16 + l15;
        #pragma unroll
        for (int r = 0; r < 4; ++r)
          C[(size_t)(row + r) * N + col] = (OutT)acc[i][j][r];
      }
    }
  }
}

__global__ __launch_bounds__(256) void gemm_qkv(const bf16_t* __restrict__ xb,
                                                const bf16_t* __restrict__ Wqt,
                                                const bf16_t* __restrict__ Wkt,
                                                const bf16_t* __restrict__ Wvt,
                                                bf16_t* __restrict__ Q,
                                                bf16_t* __restrict__ K,
                                                bf16_t* __restrict__ Vtg) {
  const bf16_t* Bt = (blockIdx.z == 0) ? Wqt : (blockIdx.z == 1) ? Wkt : Wvt;
  bf16_t* C = (blockIdx.z == 0) ? Q : (blockIdx.z == 1) ? K : Vtg;
  gemm_bt_body<bf16_t>(xb, Bt, C, 4096, 2048, 1024, blockIdx.z == 2);
}

__global__ __launch_bounds__(256) void gemm_out(const bf16_t* __restrict__ Ob,
                                                const bf16_t* __restrict__ Wot,
                                                float* __restrict__ out) {
  gemm_bt_body<float>(Ob, Wot, out, 4096, 1024, 1024, false);
}

// ---------------------------------------------------------------- attention
// grid: (8 tile-pairs, 32 b*h), 512 threads (8 waves). Block handles q-tiles
// {p, 15-p} of 128 queries each -> uniform 34 key-tile iterations per block.
// Q,K layout: [b*2048+s][comp*1024+h*64+d]. V pre-transposed:
// Vtg[b][comp*1024+h*64+d][s]. Softmax without max-subtraction (|s| <~ 2,
// mathematically exact); row-sum via MFMA with ones B-operand.

__global__ __launch_bounds__(512)
void attn_kernel(const bf16_t* __restrict__ Qg, const bf16_t* __restrict__ Kg,
                 const bf16_t* __restrict__ Vtg, bf16_t* __restrict__ Og,
                 const float* __restrict__ lamp) {
  __shared__ bf16_t Ks[2][64 * 68];  // [comp][key*68 + d]   (pad 68: stride 34 dw == 2 mod 32)
  __shared__ bf16_t Vt[2][64 * 68];  // [comp][d*68 + key]
  __shared__ bf16_t Ps[8][16 * 68];  // [wave][qrow*68 + key]

  const int tid = threadIdx.x;
  const int w = tid >> 6, lane = tid & 63;
  const int g = lane >> 4, l15 = lane & 15;
  const int p = blockIdx.x;                  // 0..7
  const int b = blockIdx.y >> 4, h = blockIdx.y & 15;
  const int rowB = b * 2048;
  const float lam = *lamp;
  const float cexp = 0.125f * 1.44269504088896340736f;  // scale * log2(e)

  const bf16_t oneb = (bf16_t)1.0f;
  const bf16x8 ones = {oneb, oneb, oneb, oneb, oneb, oneb, oneb, oneb};

  uint4 rg[4];
  auto issue = [&](int j0) {
    #pragma unroll
    for (int t = 0; t < 2; ++t) {
      int id = tid + 512 * t;
      int comp = id >> 9, key = (id >> 3) & 63, c = id & 7;
      rg[t] = *reinterpret_cast<const uint4*>(
          Kg + (size_t)(rowB + j0 + key) * 2048 + comp * 1024 + h * 64 + c * 8);
    }
    #pragma unroll
    for (int t = 0; t < 2; ++t) {
      int id = tid + 512 * t;
      int comp = id >> 9, d = (id >> 3) & 63, c = id & 7;
      rg[2 + t] = *reinterpret_cast<const uint4*>(
          Vtg + ((size_t)(b * 2048 + comp * 1024 + h * 64 + d)) * 2048 + j0 + c * 8);
    }
  };
  auto commit = [&]() {
    #pragma unroll
    for (int t = 0; t < 2; ++t) {
      int id = tid + 512 * t;
      int comp = id >> 9, key = (id >> 3) & 63, c = id & 7;
      *reinterpret_cast<uint4*>(&Ks[comp][key * 68 + c * 8]) = rg[t];
    }
    #pragma unroll
    for (int t = 0; t < 2; ++t) {
      int id = tid + 512 * t;
      int comp = id >> 9, d = (id >> 3) & 63, c = id & 7;
      *reinterpret_cast<uint4*>(&Vt[comp][d * 68 + c * 8]) = rg[2 + t];
    }
  };

  #pragma unroll 1
  for (int tt = 0; tt < 2; ++tt) {
    const int q0 = (tt == 0 ? p : 15 - p) * 128;

    // Q fragments straight from global (wave w owns rows q0+w*16 .. +15)
    bf16x8 qf[2][2];
    #pragma unroll
    for (int comp = 0; comp < 2; ++comp)
      #pragma unroll
      for (int ks = 0; ks < 2; ++ks)
        qf[comp][ks] = *reinterpret_cast<const bf16x8*>(
            Qg + (size_t)(rowB + q0 + w * 16 + l15) * 2048 + comp * 1024 +
            h * 64 + ks * 32 + g * 8);

    f32x4 o[2][4] = {};
    f32x4 lsum[2] = {};
    const int jmax = q0 + 64;

    issue(0);
    #pragma unroll 1
    for (int j0 = 0; j0 <= jmax; j0 += 64) {
      __syncthreads();   // all waves done reading prev K/V tile
      commit();          // waits this tile's loads (issued one compute ago)
      __syncthreads();   // staging visible
      if (j0 < jmax) issue(j0 + 64);  // prefetch next tile under compute
      const bool maskt = (j0 + 64 > q0);

      #pragma unroll
      for (int comp = 0; comp < 2; ++comp) {
        // ---- S = Q K^T  (C: q-row = 4g+r, key = n*16 + l15)
        f32x4 s[4];
        #pragma unroll
        for (int n = 0; n < 4; ++n) {
          bf16x8 kf0 = *reinterpret_cast<const bf16x8*>(&Ks[comp][(n * 16 + l15) * 68 + g * 8]);
          bf16x8 kf1 = *reinterpret_cast<const bf16x8*>(&Ks[comp][(n * 16 + l15) * 68 + 32 + g * 8]);
          f32x4 z = {0.f, 0.f, 0.f, 0.f};
          z = mfma16(qf[comp][0], kf0, z);
          z = mfma16(qf[comp][1], kf1, z);
          s[n] = z;
        }
        // ---- P = exp(S*scale) (no max subtraction), causal mask, pack to LDS
        #pragma unroll
        for (int n = 0; n < 4; ++n) {
          #pragma unroll
          for (int r = 0; r < 4; ++r) {
            float pv = __builtin_exp2f(s[n][r] * cexp);
            if (maskt) {
              int keyg = j0 + n * 16 + l15;
              int qg = q0 + w * 16 + 4 * g + r;
              if (keyg > qg) pv = 0.f;
            }
            Ps[w][(4 * g + r) * 68 + n * 16 + l15] = (bf16_t)pv;
          }
        }
        // ---- O += P V ; rowsum via ones-column MFMA
        #pragma unroll
        for (int ks = 0; ks < 2; ++ks) {
          bf16x8 pa = *reinterpret_cast<const bf16x8*>(&Ps[w][l15 * 68 + ks * 32 + g * 8]);
          lsum[comp] = mfma16(pa, ones, lsum[comp]);
          #pragma unroll
          for (int nd = 0; nd < 4; ++nd) {
            bf16x8 vb = *reinterpret_cast<const bf16x8*>(
                &Vt[comp][(nd * 16 + l15) * 68 + ks * 32 + g * 8]);
            o[comp][nd] = mfma16(pa, vb, o[comp][nd]);
          }
        }
      }
    }

    // ---- epilogue: (o1/l1 - lam*o2/l2) * 0.2
    #pragma unroll
    for (int r = 0; r < 4; ++r) {
      float i1 = 1.f / lsum[0][r];
      float i2 = lam / lsum[1][r];
      int row = rowB + q0 + w * 16 + 4 * g + r;
      #pragma unroll
      for (int nd = 0; nd < 4; ++nd) {
        float val = (o[0][nd][r] * i1 - o[1][nd][r] * i2) * 0.2f;
        Og[(size_t)row * 1024 + h * 64 + nd * 16 + l15] = (bf16_t)val;
      }
    }
  }
}

// ---------------------------------------------------------------- launch

extern "C" void kernel_launch(void* const* d_in, const int* in_sizes, int n_in,
                              void* d_out, int out_size, void* d_ws, size_t ws_size,
                              hipStream_t stream) {
  const float* x   = (const float*)d_in[0];
  const float* Wq  = (const float*)d_in[1];
  const float* Wk  = (const float*)d_in[2];
  const float* Wv  = (const float*)d_in[3];
  const float* Wo  = (const float*)d_in[4];
  const float* lq1 = (const float*)d_in[5];
  const float* lk1 = (const float*)d_in[6];
  const float* lq2 = (const float*)d_in[7];
  const float* lk2 = (const float*)d_in[8];
  float* out = (float*)d_out;

  char* ws = (char*)d_ws;
  size_t off = 0;
  auto alloc = [&](size_t bytes) -> char* {
    char* p = ws + off;
    off += (bytes + 255) & ~(size_t)255;
    return p;
  };
  bf16_t* xb  = (bf16_t*)alloc((size_t)4096 * 1024 * 2);
  bf16_t* Wqt = (bf16_t*)alloc((size_t)2048 * 1024 * 2);
  bf16_t* Wkt = (bf16_t*)alloc((size_t)2048 * 1024 * 2);
  bf16_t* Wvt = (bf16_t*)alloc((size_t)2048 * 1024 * 2);
  bf16_t* Wot = (bf16_t*)alloc((size_t)1024 * 1024 * 2);
  bf16_t* Qb  = (bf16_t*)alloc((size_t)4096 * 2048 * 2);
  bf16_t* Kb  = (bf16_t*)alloc((size_t)4096 * 2048 * 2);
  bf16_t* Vtg = (bf16_t*)alloc((size_t)4096 * 2048 * 2);
  bf16_t* Ob  = (bf16_t*)alloc((size_t)4096 * 1024 * 2);
  float*  lamp = (float*)alloc(256);

  lam_kernel<<<1, 64, 0, stream>>>(lq1, lk1, lq2, lk2, lamp);
  cvt_x_kernel<<<4096, 256, 0, stream>>>(x, xb);
  transpose_cvt<<<dim3(64, 32), dim3(32, 8), 0, stream>>>(Wq, Wqt, 1024, 2048);
  transpose_cvt<<<dim3(64, 32), dim3(32, 8), 0, stream>>>(Wk, Wkt, 1024, 2048);
  transpose_cvt<<<dim3(64, 32), dim3(32, 8), 0, stream>>>(Wv, Wvt, 1024, 2048);
  transpose_cvt<<<dim3(32, 32), dim3(32, 8), 0, stream>>>(Wo, Wot, 1024, 1024);
  gemm_qkv<<<dim3(16, 32, 3), 256, 0, stream>>>(xb, Wqt, Wkt, Wvt, Qb, Kb, Vtg);
  attn_kernel<<<dim3(8, 32), 512, 0, stream>>>(Qb, Kb, Vtg, Ob, lamp);
  gemm_out<<<dim3(8, 32), 256, 0, stream>>>(Ob, Wot, out);
}

// Round 3
// 216.656 us; speedup vs baseline: 2.0632x; 1.2005x over previous
//
#include <hip/hip_runtime.h>
#include <hip/hip_bf16.h>

typedef __bf16 bf16_t;
typedef bf16_t bf16x8 __attribute__((ext_vector_type(8)));
typedef float f32x4 __attribute__((ext_vector_type(4)));
typedef float f32x16 __attribute__((ext_vector_type(16)));

static __device__ __forceinline__ f32x4 mfma16(bf16x8 a, bf16x8 b, f32x4 c) {
  return __builtin_amdgcn_mfma_f32_16x16x32_bf16(a, b, c, 0, 0, 0);
}
static __device__ __forceinline__ f32x16 mfma32(bf16x8 a, bf16x8 b, f32x16 c) {
  return __builtin_amdgcn_mfma_f32_32x32x16_bf16(a, b, c, 0, 0, 0);
}

static __device__ __forceinline__ void gload_lds16(const bf16_t* g, bf16_t* l) {
  __builtin_amdgcn_global_load_lds(
      (const __attribute__((address_space(1))) void*)g,
      (__attribute__((address_space(3))) void*)l, 16, 0, 0);
}

static __device__ __forceinline__ unsigned pkbf(float a, float b) {
  union { bf16_t h[2]; unsigned u; } p;
  p.h[0] = (bf16_t)a; p.h[1] = (bf16_t)b;
  return p.u;
}
// swaps a.hi-lanes with b.lo-lanes: a' = w_lo, b' = w_hi (see derivation)
static __device__ __forceinline__ void pl32swap(unsigned& a, unsigned& b) {
  asm volatile("v_permlane32_swap_b32 %0, %1" : "+v"(a), "+v"(b));
}

// ---------------------------------------------------------------- tiny kernels

__global__ __launch_bounds__(64) void lam_kernel(const float* __restrict__ lq1,
                                                 const float* __restrict__ lk1,
                                                 const float* __restrict__ lq2,
                                                 const float* __restrict__ lk2,
                                                 float* __restrict__ lamp) {
  int l = threadIdx.x;
  float a = lq1[l] * lk1[l];
  float b = lq2[l] * lk2[l];
  #pragma unroll
  for (int msk = 32; msk; msk >>= 1) {
    a += __shfl_xor(a, msk);
    b += __shfl_xor(b, msk);
  }
  if (l == 0) lamp[0] = __expf(a) - __expf(b) + 0.8f;
}

__global__ __launch_bounds__(256) void cvt_x_kernel(const float* __restrict__ x,
                                                    bf16_t* __restrict__ xb) {
  int i = (blockIdx.x * 256 + threadIdx.x) * 4;
  float4 v = *reinterpret_cast<const float4*>(x + i);
  union { bf16_t h[4]; uint2 u; } pk;
  pk.h[0] = (bf16_t)v.x; pk.h[1] = (bf16_t)v.y;
  pk.h[2] = (bf16_t)v.z; pk.h[3] = (bf16_t)v.w;
  *reinterpret_cast<uint2*>(xb + i) = pk.u;
}

// W: [K][N] fp32 row-major  ->  Wt: [N][K] bf16 row-major
__global__ __launch_bounds__(256) void transpose_cvt(const float* __restrict__ W,
                                                     bf16_t* __restrict__ Wt,
                                                     int K, int N) {
  __shared__ float tile[32][33];
  int n0 = blockIdx.x * 32, k0 = blockIdx.y * 32;
  int x = threadIdx.x, y = threadIdx.y;  // 32 x 8
  #pragma unroll
  for (int i = 0; i < 32; i += 8)
    tile[y + i][x] = W[(size_t)(k0 + y + i) * N + n0 + x];
  __syncthreads();
  #pragma unroll
  for (int i = 0; i < 32; i += 8)
    Wt[(size_t)(n0 + y + i) * K + k0 + x] = (bf16_t)tile[x][y + i];
}

// ---------------------------------------------------------------- GEMM (A[M][K] x Bt[N][K]^T)

template <typename OutT>
static __device__ __forceinline__ void gemm_bt_body(const bf16_t* __restrict__ A,
                                                    const bf16_t* __restrict__ Bt,
                                                    OutT* __restrict__ C,
                                                    int M, int N, int K,
                                                    bool vtrans) {
  __shared__ bf16_t As[128 * 32];
  __shared__ bf16_t Bs[128 * 32];
  const int tid = threadIdx.x;
  const int w = tid >> 6, lane = tid & 63;
  const int g = lane >> 4, l15 = lane & 15;
  const int wm = w >> 1, wn = w & 1;
  const int rowBase = blockIdx.y * 128, colBase = blockIdx.x * 128;

  const int c0 = 2 * w, c1 = 2 * w + 1;
  const int srow0 = 16 * c0 + (lane >> 2);
  const int srow1 = 16 * c1 + (lane >> 2);
  const int scol = (lane & 3) * 8;

  f32x4 acc[4][4] = {};

  for (int k0 = 0; k0 < K; k0 += 32) {
    __syncthreads();
    gload_lds16(A + (size_t)(rowBase + srow0) * K + k0 + scol, &As[c0 * 512]);
    gload_lds16(A + (size_t)(rowBase + srow1) * K + k0 + scol, &As[c1 * 512]);
    gload_lds16(Bt + (size_t)(colBase + srow0) * K + k0 + scol, &Bs[c0 * 512]);
    gload_lds16(Bt + (size_t)(colBase + srow1) * K + k0 + scol, &Bs[c1 * 512]);
    __syncthreads();

    bf16x8 bfr[4];
    #pragma unroll
    for (int j = 0; j < 4; ++j)
      bfr[j] = *reinterpret_cast<const bf16x8*>(&Bs[(wn * 64 + j * 16 + l15) * 32 + g * 8]);
    #pragma unroll
    for (int i = 0; i < 4; ++i) {
      bf16x8 afr = *reinterpret_cast<const bf16x8*>(&As[(wm * 64 + i * 16 + l15) * 32 + g * 8]);
      #pragma unroll
      for (int j = 0; j < 4; ++j)
        acc[i][j] = mfma16(afr, bfr[j], acc[i][j]);
    }
  }

  if (vtrans) {
    #pragma unroll
    for (int i = 0; i < 4; ++i) {
      #pragma unroll
      for (int j = 0; j < 4; ++j) {
        int row = rowBase + wm * 64 + i * 16 + 4 * g;  // global s in [0,4096)
        int col = colBase + wn * 64 + j * 16 + l15;    // [0,2048)
        int bb = row >> 11, s = row & 2047;
        union { bf16_t h[4]; uint2 u; } pk;
        #pragma unroll
        for (int r = 0; r < 4; ++r) pk.h[r] = (bf16_t)acc[i][j][r];
        *reinterpret_cast<uint2*>(
            (bf16_t*)C + ((size_t)bb * 2048 + col) * 2048 + s) = pk.u;
      }
    }
  } else {
    #pragma unroll
    for (int i = 0; i < 4; ++i) {
      #pragma unroll
      for (int j = 0; j < 4; ++j) {
        int row = rowBase + wm * 64 + i * 16 + 4 * g;
        int col = colBase + wn * 64 + j * 16 + l15;
        #pragma unroll
        for (int r = 0; r < 4; ++r)
          C[(size_t)(row + r) * N + col] = (OutT)acc[i][j][r];
      }
    }
  }
}

__global__ __launch_bounds__(256) void gemm_qkv(const bf16_t* __restrict__ xb,
                                                const bf16_t* __restrict__ Wqt,
                                                const bf16_t* __restrict__ Wkt,
                                                const bf16_t* __restrict__ Wvt,
                                                bf16_t* __restrict__ Q,
                                                bf16_t* __restrict__ K,
                                                bf16_t* __restrict__ Vtg) {
  const bf16_t* Bt = (blockIdx.z == 0) ? Wqt : (blockIdx.z == 1) ? Wkt : Wvt;
  bf16_t* C = (blockIdx.z == 0) ? Q : (blockIdx.z == 1) ? K : Vtg;
  gemm_bt_body<bf16_t>(xb, Bt, C, 4096, 2048, 1024, blockIdx.z == 2);
}

__global__ __launch_bounds__(256) void gemm_out(const bf16_t* __restrict__ Ob,
                                                const bf16_t* __restrict__ Wot,
                                                float* __restrict__ out) {
  gemm_bt_body<float>(Ob, Wot, out, 4096, 1024, 1024, false);
}

// ---------------------------------------------------------------- attention
// 512 blocks x 256 thr (4 waves). Block = one 128-row q-tile (tile = 15-(bx>>5),
// longest first), bh = bx&31. Wave owns 32 q-rows (QBLK=32, 32x32x16 MFMA).
// Swapped QK^T: mfma(K,Q) -> P lane-local (col=q=lane&31); softmax in-register
// (no max subtraction; |s|<~2); PV A-operand built via cvt_pk + permlane32_swap.
// K/V staged via global_load_lds into XOR-swizzled linear LDS (byte^=((row&7)<<4)
// via pre-swizzled source chunks), double-buffered 2-phase pipeline.

__global__ __launch_bounds__(256, 2)
void attn_kernel(const bf16_t* __restrict__ Qg, const bf16_t* __restrict__ Kg,
                 const bf16_t* __restrict__ Vtg, bf16_t* __restrict__ Og,
                 const float* __restrict__ lamp) {
  // buffer layout (bytes): [0,8K) K comp0 [key][128B] | [8K,16K) K comp1
  //                        [16K,24K) V comp0 [d][128B] | [24K,32K) V comp1
  __shared__ bf16_t lds0[16384];
  __shared__ bf16_t lds1[16384];
  __shared__ float lsArr[4][2][32];

  const int tid = threadIdx.x;
  const int w = tid >> 6, lane = tid & 63;
  const int l31 = lane & 31, hi = lane >> 5;
  const int sw7 = l31 & 7;
  const int bx = blockIdx.x;
  const int tile = 15 - (bx >> 5);
  const int bh = bx & 31;
  const int b = bh >> 4, h = bh & 15;
  const int rowB = b * 2048;
  const int q0 = tile * 128;
  const float lam = *lamp;
  const float cexp = 0.125f * 1.44269504088896340736f;  // scale * log2(e)

  // ---- staging constants (wave w stages section w: K0,K1,V0,V1)
  const int lk = lane >> 3;                   // row-within-8
  const int swc = (lane & 7) ^ (lk & 7);      // pre-swizzled source chunk
  const int compw = w & 1;
  const size_t kbase = (size_t)(rowB + lk) * 2048 + compw * 1024 + h * 64 + swc * 8;
  const size_t vbase = ((size_t)b * 2048 + compw * 1024 + h * 64 + lk) * 2048 + swc * 8;

  auto stage = [&](bf16_t* buf, int j0) {
    char* bufb = (char*)buf;
    if (w < 2) {
      const bf16_t* src = Kg + kbase + (size_t)j0 * 2048;
      #pragma unroll
      for (int t = 0; t < 8; ++t)
        gload_lds16(src + (size_t)t * (8 * 2048),
                    (bf16_t*)(bufb + (w * 8 + t) * 1024));
    } else {
      const bf16_t* src = Vtg + vbase + j0;
      #pragma unroll
      for (int t = 0; t < 8; ++t)
        gload_lds16(src + (size_t)t * (8 * 2048),
                    (bf16_t*)(bufb + (w * 8 + t) * 1024));
    }
  };

  // ---- Q fragments straight from global: wave rows q0+w*32 .. +31
  const int qg = q0 + w * 32 + l31;  // this lane's q (for P col + mask)
  bf16x8 qf[2][4];
  #pragma unroll
  for (int comp = 0; comp < 2; ++comp)
    #pragma unroll
    for (int s = 0; s < 4; ++s)
      qf[comp][s] = *reinterpret_cast<const bf16x8*>(
          Qg + (size_t)(rowB + qg) * 2048 + comp * 1024 + h * 64 + s * 16 + hi * 8);

  f32x16 o[2][2] = {};
  float ls[2] = {0.f, 0.f};
  const int jmax = q0 + 64;

  stage(lds0, 0);
  __syncthreads();

  int cur = 0;
  #pragma unroll 1
  for (int j0 = 0; j0 <= jmax; j0 += 64) {
    bf16_t* bc = cur ? lds1 : lds0;
    bf16_t* bn = cur ? lds0 : lds1;
    if (j0 < jmax) stage(bn, j0 + 64);  // prefetch next tile under compute

    const char* bufb = (const char*)bc;
    const bool maskt = (j0 + 63 > q0 + w * 32);

    #pragma unroll
    for (int comp = 0; comp < 2; ++comp) {
      // ---- S' = K Q^T : C[key][q], q = lane&31, key = kb*32 + (e&3)+8*(e>>2)+4*hi
      const char* Kb = bufb + comp * 8192;
      f32x16 sA0 = {}, sA1 = {};
      #pragma unroll
      for (int s = 0; s < 4; ++s) {
        int xo = ((2 * s + hi) ^ sw7) << 4;
        bf16x8 k0 = *reinterpret_cast<const bf16x8*>(Kb + l31 * 128 + xo);
        bf16x8 k1 = *reinterpret_cast<const bf16x8*>(Kb + (32 + l31) * 128 + xo);
        sA0 = mfma32(k0, qf[comp][s], sA0);
        sA1 = mfma32(k1, qf[comp][s], sA1);
      }
      // ---- P = exp2(S*cexp), causal mask, lane-local rowsum
      float p0[16], p1[16];
      #pragma unroll
      for (int e = 0; e < 16; ++e) {
        float v0 = __builtin_exp2f(sA0[e] * cexp);
        float v1 = __builtin_exp2f(sA1[e] * cexp);
        if (maskt) {
          int krow = (e & 3) + 8 * (e >> 2) + 4 * hi;
          if (j0 + krow > qg) v0 = 0.f;
          if (j0 + 32 + krow > qg) v1 = 0.f;
        }
        p0[e] = v0; p1[e] = v1;
        ls[comp] += v0 + v1;
      }
      // ---- build PV A-fragments in-register: pa[s] holds keys s*16+8*hi+j
      bf16x8 pa[4];
      #pragma unroll
      for (int sp = 0; sp < 2; ++sp) {
        {
          unsigned u0 = pkbf(p0[8 * sp + 0], p0[8 * sp + 1]);
          unsigned u1 = pkbf(p0[8 * sp + 2], p0[8 * sp + 3]);
          unsigned v0 = pkbf(p0[8 * sp + 4], p0[8 * sp + 5]);
          unsigned v1 = pkbf(p0[8 * sp + 6], p0[8 * sp + 7]);
          pl32swap(u0, v0);  // u0 -> words j0..1, v0 -> words j4..5
          pl32swap(u1, v1);
          union { uint4 u; bf16x8 f; } cvt;
          cvt.u = make_uint4(u0, u1, v0, v1);
          pa[sp] = cvt.f;
        }
        {
          unsigned u0 = pkbf(p1[8 * sp + 0], p1[8 * sp + 1]);
          unsigned u1 = pkbf(p1[8 * sp + 2], p1[8 * sp + 3]);
          unsigned v0 = pkbf(p1[8 * sp + 4], p1[8 * sp + 5]);
          unsigned v1 = pkbf(p1[8 * sp + 6], p1[8 * sp + 7]);
          pl32swap(u0, v0);
          pl32swap(u1, v1);
          union { uint4 u; bf16x8 f; } cvt;
          cvt.u = make_uint4(u0, u1, v0, v1);
          pa[2 + sp] = cvt.f;
        }
      }
      // ---- O += P V : A = pa (rows=q), B = V[d][key] from LDS
      const char* Vb = bufb + 16384 + comp * 8192;
      #pragma unroll
      for (int s = 0; s < 4; ++s) {
        int xo = ((2 * s + hi) ^ sw7) << 4;
        bf16x8 vf0 = *reinterpret_cast<const bf16x8*>(Vb + l31 * 128 + xo);
        bf16x8 vf1 = *reinterpret_cast<const bf16x8*>(Vb + (32 + l31) * 128 + xo);
        o[comp][0] = mfma32(pa[s], vf0, o[comp][0]);
        o[comp][1] = mfma32(pa[s], vf1, o[comp][1]);
      }
    }
    __syncthreads();
    cur ^= 1;
  }

  // ---- epilogue: combine lane-pair rowsums, then (o1/l1 - lam*o2/l2)*0.2
  #pragma unroll
  for (int comp = 0; comp < 2; ++comp) {
    float tot = ls[comp] + __shfl_xor(ls[comp], 32);
    lsArr[w][comp][l31] = 1.f / tot;
  }
  #pragma unroll
  for (int e = 0; e < 16; ++e) {
    int ql = (e & 3) + 8 * (e >> 2) + 4 * hi;
    float i1 = lsArr[w][0][ql];
    float i2 = lsArr[w][1][ql] * lam;
    int row = rowB + q0 + w * 32 + ql;
    size_t rb = (size_t)row * 1024 + h * 64 + l31;
    Og[rb]      = (bf16_t)((o[0][0][e] * i1 - o[1][0][e] * i2) * 0.2f);
    Og[rb + 32] = (bf16_t)((o[0][1][e] * i1 - o[1][1][e] * i2) * 0.2f);
  }
}

// ---------------------------------------------------------------- launch

extern "C" void kernel_launch(void* const* d_in, const int* in_sizes, int n_in,
                              void* d_out, int out_size, void* d_ws, size_t ws_size,
                              hipStream_t stream) {
  const float* x   = (const float*)d_in[0];
  const float* Wq  = (const float*)d_in[1];
  const float* Wk  = (const float*)d_in[2];
  const float* Wv  = (const float*)d_in[3];
  const float* Wo  = (const float*)d_in[4];
  const float* lq1 = (const float*)d_in[5];
  const float* lk1 = (const float*)d_in[6];
  const float* lq2 = (const float*)d_in[7];
  const float* lk2 = (const float*)d_in[8];
  float* out = (float*)d_out;

  char* ws = (char*)d_ws;
  size_t off = 0;
  auto alloc = [&](size_t bytes) -> char* {
    char* p = ws + off;
    off += (bytes + 255) & ~(size_t)255;
    return p;
  };
  bf16_t* xb  = (bf16_t*)alloc((size_t)4096 * 1024 * 2);
  bf16_t* Wqt = (bf16_t*)alloc((size_t)2048 * 1024 * 2);
  bf16_t* Wkt = (bf16_t*)alloc((size_t)2048 * 1024 * 2);
  bf16_t* Wvt = (bf16_t*)alloc((size_t)2048 * 1024 * 2);
  bf16_t* Wot = (bf16_t*)alloc((size_t)1024 * 1024 * 2);
  bf16_t* Qb  = (bf16_t*)alloc((size_t)4096 * 2048 * 2);
  bf16_t* Kb  = (bf16_t*)alloc((size_t)4096 * 2048 * 2);
  bf16_t* Vtg = (bf16_t*)alloc((size_t)4096 * 2048 * 2);
  bf16_t* Ob  = (bf16_t*)alloc((size_t)4096 * 1024 * 2);
  float*  lamp = (float*)alloc(256);

  lam_kernel<<<1, 64, 0, stream>>>(lq1, lk1, lq2, lk2, lamp);
  cvt_x_kernel<<<4096, 256, 0, stream>>>(x, xb);
  transpose_cvt<<<dim3(64, 32), dim3(32, 8), 0, stream>>>(Wq, Wqt, 1024, 2048);
  transpose_cvt<<<dim3(64, 32), dim3(32, 8), 0, stream>>>(Wk, Wkt, 1024, 2048);
  transpose_cvt<<<dim3(64, 32), dim3(32, 8), 0, stream>>>(Wv, Wvt, 1024, 2048);
  transpose_cvt<<<dim3(32, 32), dim3(32, 8), 0, stream>>>(Wo, Wot, 1024, 1024);
  gemm_qkv<<<dim3(16, 32, 3), 256, 0, stream>>>(xb, Wqt, Wkt, Wvt, Qb, Kb, Vtg);
  attn_kernel<<<512, 256, 0, stream>>>(Qb, Kb, Vtg, Ob, lamp);
  gemm_out<<<dim3(8, 32), 256, 0, stream>>>(Ob, Wot, out);
}

// Round 4
// 198.696 us; speedup vs baseline: 2.2497x; 1.0904x over previous
//
#include <hip/hip_runtime.h>
#include <hip/hip_bf16.h>

typedef __bf16 bf16_t;
typedef bf16_t bf16x8 __attribute__((ext_vector_type(8)));
typedef float f32x4 __attribute__((ext_vector_type(4)));
typedef float f32x16 __attribute__((ext_vector_type(16)));

static __device__ __forceinline__ f32x4 mfma16(bf16x8 a, bf16x8 b, f32x4 c) {
  return __builtin_amdgcn_mfma_f32_16x16x32_bf16(a, b, c, 0, 0, 0);
}
static __device__ __forceinline__ f32x16 mfma32(bf16x8 a, bf16x8 b, f32x16 c) {
  return __builtin_amdgcn_mfma_f32_32x32x16_bf16(a, b, c, 0, 0, 0);
}

static __device__ __forceinline__ void gload_lds16(const bf16_t* g, bf16_t* l) {
  __builtin_amdgcn_global_load_lds(
      (const __attribute__((address_space(1))) void*)g,
      (__attribute__((address_space(3))) void*)l, 16, 0, 0);
}

static __device__ __forceinline__ unsigned pkbf(float a, float b) {
  union { bf16_t h[2]; unsigned u; } p;
  p.h[0] = (bf16_t)a; p.h[1] = (bf16_t)b;
  return p.u;
}
static __device__ __forceinline__ void pl32swap(unsigned& a, unsigned& b) {
  asm volatile("v_permlane32_swap_b32 %0, %1" : "+v"(a), "+v"(b));
}

// ---------------------------------------------------------------- tiny kernels

__global__ __launch_bounds__(64) void lam_kernel(const float* __restrict__ lq1,
                                                 const float* __restrict__ lk1,
                                                 const float* __restrict__ lq2,
                                                 const float* __restrict__ lk2,
                                                 float* __restrict__ lamp) {
  int l = threadIdx.x;
  float a = lq1[l] * lk1[l];
  float b = lq2[l] * lk2[l];
  #pragma unroll
  for (int msk = 32; msk; msk >>= 1) {
    a += __shfl_xor(a, msk);
    b += __shfl_xor(b, msk);
  }
  if (l == 0) lamp[0] = __expf(a) - __expf(b) + 0.8f;
}

__global__ __launch_bounds__(256) void cvt_x_kernel(const float* __restrict__ x,
                                                    bf16_t* __restrict__ xb) {
  int i = (blockIdx.x * 256 + threadIdx.x) * 4;
  float4 v = *reinterpret_cast<const float4*>(x + i);
  union { bf16_t h[4]; uint2 u; } pk;
  pk.h[0] = (bf16_t)v.x; pk.h[1] = (bf16_t)v.y;
  pk.h[2] = (bf16_t)v.z; pk.h[3] = (bf16_t)v.w;
  *reinterpret_cast<uint2*>(xb + i) = pk.u;
}

// W: [K][N] fp32 row-major  ->  Wt: [N][K] bf16 row-major
__global__ __launch_bounds__(256) void transpose_cvt(const float* __restrict__ W,
                                                     bf16_t* __restrict__ Wt,
                                                     int K, int N) {
  __shared__ float tile[32][33];
  int n0 = blockIdx.x * 32, k0 = blockIdx.y * 32;
  int x = threadIdx.x, y = threadIdx.y;  // 32 x 8
  #pragma unroll
  for (int i = 0; i < 32; i += 8)
    tile[y + i][x] = W[(size_t)(k0 + y + i) * N + n0 + x];
  __syncthreads();
  #pragma unroll
  for (int i = 0; i < 32; i += 8)
    Wt[(size_t)(n0 + y + i) * K + k0 + x] = (bf16_t)tile[x][y + i];
}

// ---------------------------------------------------------------- GEMM (A[M][K] x Bt[N][K]^T)

template <typename OutT>
static __device__ __forceinline__ void gemm_bt_body(const bf16_t* __restrict__ A,
                                                    const bf16_t* __restrict__ Bt,
                                                    OutT* __restrict__ C,
                                                    int M, int N, int K,
                                                    bool vtrans) {
  __shared__ bf16_t As[128 * 32];
  __shared__ bf16_t Bs[128 * 32];
  const int tid = threadIdx.x;
  const int w = tid >> 6, lane = tid & 63;
  const int g = lane >> 4, l15 = lane & 15;
  const int wm = w >> 1, wn = w & 1;

  // T1: XCD-contiguous block swizzle (n = gridDim.x*gridDim.y divisible by 8)
  const int nbx = gridDim.x;
  const int idx = blockIdx.y * nbx + blockIdx.x;
  const int qq = (nbx * gridDim.y) >> 3;
  const int sidx = (idx & 7) * qq + (idx >> 3);
  const int rowBase = (sidx / nbx) * 128, colBase = (sidx % nbx) * 128;

  const int c0 = 2 * w, c1 = 2 * w + 1;
  const int srow0 = 16 * c0 + (lane >> 2);
  const int srow1 = 16 * c1 + (lane >> 2);
  const int scol = (lane & 3) * 8;

  f32x4 acc[4][4] = {};

  for (int k0 = 0; k0 < K; k0 += 32) {
    __syncthreads();
    gload_lds16(A + (size_t)(rowBase + srow0) * K + k0 + scol, &As[c0 * 512]);
    gload_lds16(A + (size_t)(rowBase + srow1) * K + k0 + scol, &As[c1 * 512]);
    gload_lds16(Bt + (size_t)(colBase + srow0) * K + k0 + scol, &Bs[c0 * 512]);
    gload_lds16(Bt + (size_t)(colBase + srow1) * K + k0 + scol, &Bs[c1 * 512]);
    __syncthreads();

    bf16x8 bfr[4];
    #pragma unroll
    for (int j = 0; j < 4; ++j)
      bfr[j] = *reinterpret_cast<const bf16x8*>(&Bs[(wn * 64 + j * 16 + l15) * 32 + g * 8]);
    #pragma unroll
    for (int i = 0; i < 4; ++i) {
      bf16x8 afr = *reinterpret_cast<const bf16x8*>(&As[(wm * 64 + i * 16 + l15) * 32 + g * 8]);
      #pragma unroll
      for (int j = 0; j < 4; ++j)
        acc[i][j] = mfma16(afr, bfr[j], acc[i][j]);
    }
  }

  if (vtrans) {
    #pragma unroll
    for (int i = 0; i < 4; ++i) {
      #pragma unroll
      for (int j = 0; j < 4; ++j) {
        int row = rowBase + wm * 64 + i * 16 + 4 * g;  // global s in [0,4096)
        int col = colBase + wn * 64 + j * 16 + l15;    // [0,2048)
        int bb = row >> 11, s = row & 2047;
        union { bf16_t h[4]; uint2 u; } pk;
        #pragma unroll
        for (int r = 0; r < 4; ++r) pk.h[r] = (bf16_t)acc[i][j][r];
        *reinterpret_cast<uint2*>(
            (bf16_t*)C + ((size_t)bb * 2048 + col) * 2048 + s) = pk.u;
      }
    }
  } else {
    #pragma unroll
    for (int i = 0; i < 4; ++i) {
      #pragma unroll
      for (int j = 0; j < 4; ++j) {
        int row = rowBase + wm * 64 + i * 16 + 4 * g;
        int col = colBase + wn * 64 + j * 16 + l15;
        #pragma unroll
        for (int r = 0; r < 4; ++r)
          C[(size_t)(row + r) * N + col] = (OutT)acc[i][j][r];
      }
    }
  }
}

__global__ __launch_bounds__(256) void gemm_qkv(const bf16_t* __restrict__ xb,
                                                const bf16_t* __restrict__ Wqt,
                                                const bf16_t* __restrict__ Wkt,
                                                const bf16_t* __restrict__ Wvt,
                                                bf16_t* __restrict__ Q,
                                                bf16_t* __restrict__ K,
                                                bf16_t* __restrict__ Vtg) {
  const bf16_t* Bt = (blockIdx.z == 0) ? Wqt : (blockIdx.z == 1) ? Wkt : Wvt;
  bf16_t* C = (blockIdx.z == 0) ? Q : (blockIdx.z == 1) ? K : Vtg;
  gemm_bt_body<bf16_t>(xb, Bt, C, 4096, 2048, 1024, blockIdx.z == 2);
}

__global__ __launch_bounds__(256) void gemm_out(const bf16_t* __restrict__ Ob,
                                                const bf16_t* __restrict__ Wot,
                                                float* __restrict__ out) {
  gemm_bt_body<float>(Ob, Wot, out, 4096, 1024, 1024, false);
}

// ---------------------------------------------------------------- attention
// 256 blocks x 512 thr (8 waves). Block = pair of q-tiles {p, 15-p} (128 rows
// each) processed sequentially with KVBLK=128 -> exactly 17 iterations per
// block, 1 block/CU: perfect balance. Waves: rowg = w&3 (32 q-rows),
// keyh = w>>2 (64-key half). Key-half partials (o, ls) combine by simple
// addition (no-max softmax) via LDS at each phase end.
// LDS buffer (64KB x2): K [comp*128+key][128B swz] | V at +32KB [comp*64+d][256B swz].

__global__ __launch_bounds__(512, 1)
void attn_kernel(const bf16_t* __restrict__ Qg, const bf16_t* __restrict__ Kg,
                 const bf16_t* __restrict__ Vtg, bf16_t* __restrict__ Og,
                 const float* __restrict__ lamp) {
  __shared__ __align__(16) char ldsbuf[2][65536];
  __shared__ float lsArr[4][2][32];

  const int tid = threadIdx.x;
  const int w = tid >> 6, lane = tid & 63;
  const int l31 = lane & 31, hi = lane >> 5;
  const int sw7 = l31 & 7;
  const int rowg = w & 3, keyh = w >> 2;
  const int bx = blockIdx.x;
  const int p = bx >> 5;            // pair 0..7 -> tiles {p, 15-p}
  const int bh = bx & 31;
  const int b = bh >> 4, h = bh & 15;
  const int rowB = b * 2048;
  const float lam = *lamp;
  const float cexp = 0.125f * 1.44269504088896340736f;  // scale * log2(e)

  // ---- staging constants
  const int lk8 = lane >> 3;               // K: row-within-8
  const int sc8 = (lane & 7) ^ lk8;        // K: pre-swizzled source chunk
  const int lk4 = lane >> 4;               // V: row-within-4
  const int wv = (w - 4) & 3;
  const size_t kOff = (size_t)(rowB + ((w & 1) << 6) + lk8) * 2048 +
                      (w >> 1) * 1024 + h * 64 + sc8 * 8;           // w<4
  const size_t vOff = ((size_t)b * 2048 + (wv >> 1) * 1024 + h * 64 +
                       ((wv & 1) << 5) + lk4) * 2048;               // w>=4

  auto stage = [&](char* bufb, int j0) {
    if (w < 4) {
      const bf16_t* src = Kg + kOff + (size_t)j0 * 2048;
      char* dst = bufb + w * 8192;
      #pragma unroll
      for (int t = 0; t < 8; ++t)
        gload_lds16(src + (size_t)t * (8 * 2048), (bf16_t*)(dst + t * 1024));
    } else {
      const bf16_t* src = Vtg + vOff + j0;
      char* dst = bufb + 32768 + wv * 8192;
      #pragma unroll
      for (int t = 0; t < 8; ++t) {
        int sc16 = (lane & 15) ^ (((t & 1) << 2) + lk4);
        gload_lds16(src + (size_t)t * (4 * 2048) + sc16 * 8,
                    (bf16_t*)(dst + t * 1024));
      }
    }
  };

  f32x16 o[2][2];
  float ls[2];
  bf16x8 qf[2][4];

  auto sched_j0 = [&](int i) { return (i > p ? (i - p - 1) : i) << 7; };

  // ---- phase-end: combine key-half partials via LDS scratch (freed buffer),
  // then normalize + store. Waves 4-7 donate, waves 0-3 finalize.
  auto finalize = [&](int q0, char* scratch) {
    float* sf = (float*)scratch;
    #pragma unroll
    for (int rd = 0; rd < 4; ++rd) {
      const int comp = rd >> 1, db = rd & 1;
      __syncthreads();
      if (w >= 4) {
        float* bp = sf + (size_t)((w - 4) * 64 + lane) * 17;
        #pragma unroll
        for (int e = 0; e < 16; ++e) bp[e] = o[comp][db][e];
        if (db == 0) bp[16] = ls[comp];
      }
      __syncthreads();
      if (w < 4) {
        const float* bp = sf + (size_t)(w * 64 + lane) * 17;
        #pragma unroll
        for (int e = 0; e < 16; ++e) o[comp][db][e] += bp[e];
        if (db == 0) ls[comp] += bp[16];
      }
    }
    __syncthreads();  // scratch reads done
    if (w < 4) {
      #pragma unroll
      for (int comp = 0; comp < 2; ++comp) {
        float tot = ls[comp] + __shfl_xor(ls[comp], 32);
        lsArr[w][comp][l31] = 1.f / tot;
      }
    }
    __syncthreads();
    if (w < 4) {
      #pragma unroll
      for (int e = 0; e < 16; ++e) {
        int ql = (e & 3) + 8 * (e >> 2) + 4 * hi;
        float i1 = lsArr[w][0][ql];
        float i2 = lsArr[w][1][ql] * lam;
        int row = rowB + q0 + w * 32 + ql;
        size_t rb = (size_t)row * 1024 + h * 64 + l31;
        Og[rb]      = (bf16_t)((o[0][0][e] * i1 - o[1][0][e] * i2) * 0.2f);
        Og[rb + 32] = (bf16_t)((o[0][1][e] * i1 - o[1][1][e] * i2) * 0.2f);
      }
    }
  };

  stage(ldsbuf[0], 0);
  __syncthreads();

  #pragma unroll 1
  for (int i = 0; i <= 16; ++i) {
    const int q0 = (i > p ? 15 - p : p) << 7;
    const int j0 = sched_j0(i);
    char* bc = ldsbuf[i & 1];
    char* bn = ldsbuf[(i + 1) & 1];
    if (i < 16) stage(bn, sched_j0(i + 1));  // prefetch under compute

    if (i == 0 || i == p + 1) {  // phase start: Q fragments + reset acc
      #pragma unroll
      for (int comp = 0; comp < 2; ++comp)
        #pragma unroll
        for (int s = 0; s < 4; ++s)
          qf[comp][s] = *reinterpret_cast<const bf16x8*>(
              Qg + (size_t)(rowB + q0 + rowg * 32 + l31) * 2048 + comp * 1024 +
              h * 64 + s * 16 + hi * 8);
      #pragma unroll
      for (int comp = 0; comp < 2; ++comp) {
        o[comp][0] = (f32x16)0.f;
        o[comp][1] = (f32x16)0.f;
        ls[comp] = 0.f;
      }
    }

    const int qg = q0 + rowg * 32 + l31;
    const bool active = (j0 + keyh * 64) <= (q0 + rowg * 32 + 31);
    if (active) {
      const bool maskt = (j0 + keyh * 64 + 63) > (q0 + rowg * 32);
      #pragma unroll
      for (int comp = 0; comp < 2; ++comp) {
        // ---- S' = K Q^T : C[key][q], q = l31, key = keyh*64 + kb*32 + krow
        const char* Kb = bc + comp * 16384 + keyh * 64 * 128;
        f32x16 sA0 = {}, sA1 = {};
        #pragma unroll
        for (int s = 0; s < 4; ++s) {
          int xo = ((2 * s + hi) ^ sw7) << 4;
          bf16x8 k0 = *reinterpret_cast<const bf16x8*>(Kb + l31 * 128 + xo);
          bf16x8 k1 = *reinterpret_cast<const bf16x8*>(Kb + (32 + l31) * 128 + xo);
          sA0 = mfma32(k0, qf[comp][s], sA0);
          sA1 = mfma32(k1, qf[comp][s], sA1);
        }
        // ---- P = exp2(S*cexp), causal mask, lane-local rowsum
        float p0[16], p1[16];
        #pragma unroll
        for (int e = 0; e < 16; ++e) {
          float v0 = __builtin_exp2f(sA0[e] * cexp);
          float v1 = __builtin_exp2f(sA1[e] * cexp);
          if (maskt) {
            int krow = (e & 3) + 8 * (e >> 2) + 4 * hi;
            if (j0 + keyh * 64 + krow > qg) v0 = 0.f;
            if (j0 + keyh * 64 + 32 + krow > qg) v1 = 0.f;
          }
          p0[e] = v0; p1[e] = v1;
          ls[comp] += v0 + v1;
        }
        // ---- PV A-fragments in-register (cvt_pk + permlane32_swap)
        bf16x8 pa[4];
        #pragma unroll
        for (int sp = 0; sp < 2; ++sp) {
          {
            unsigned u0 = pkbf(p0[8 * sp + 0], p0[8 * sp + 1]);
            unsigned u1 = pkbf(p0[8 * sp + 2], p0[8 * sp + 3]);
            unsigned v0 = pkbf(p0[8 * sp + 4], p0[8 * sp + 5]);
            unsigned v1 = pkbf(p0[8 * sp + 6], p0[8 * sp + 7]);
            pl32swap(u0, v0);
            pl32swap(u1, v1);
            union { uint4 u; bf16x8 f; } cvt;
            cvt.u = make_uint4(u0, u1, v0, v1);
            pa[sp] = cvt.f;
          }
          {
            unsigned u0 = pkbf(p1[8 * sp + 0], p1[8 * sp + 1]);
            unsigned u1 = pkbf(p1[8 * sp + 2], p1[8 * sp + 3]);
            unsigned v0 = pkbf(p1[8 * sp + 4], p1[8 * sp + 5]);
            unsigned v1 = pkbf(p1[8 * sp + 6], p1[8 * sp + 7]);
            pl32swap(u0, v0);
            pl32swap(u1, v1);
            union { uint4 u; bf16x8 f; } cvt;
            cvt.u = make_uint4(u0, u1, v0, v1);
            pa[2 + sp] = cvt.f;
          }
        }
        // ---- O += P V : B = V[d][key] (rows 256B, swizzled)
        const char* Vb = bc + 32768 + comp * 16384;
        #pragma unroll
        for (int s = 0; s < 4; ++s) {
          int sl = ((keyh * 8) | ((2 * s + hi) ^ sw7)) << 4;
          bf16x8 vf0 = *reinterpret_cast<const bf16x8*>(Vb + l31 * 256 + sl);
          bf16x8 vf1 = *reinterpret_cast<const bf16x8*>(Vb + (32 + l31) * 256 + sl);
          o[comp][0] = mfma32(pa[s], vf0, o[comp][0]);
          o[comp][1] = mfma32(pa[s], vf1, o[comp][1]);
        }
      }
    }

    if (i == p || i == 16) {
      finalize(q0, bc);      // internal barriers cover the loop barrier
    } else {
      __syncthreads();
    }
  }
}

// ---------------------------------------------------------------- launch

extern "C" void kernel_launch(void* const* d_in, const int* in_sizes, int n_in,
                              void* d_out, int out_size, void* d_ws, size_t ws_size,
                              hipStream_t stream) {
  const float* x   = (const float*)d_in[0];
  const float* Wq  = (const float*)d_in[1];
  const float* Wk  = (const float*)d_in[2];
  const float* Wv  = (const float*)d_in[3];
  const float* Wo  = (const float*)d_in[4];
  const float* lq1 = (const float*)d_in[5];
  const float* lk1 = (const float*)d_in[6];
  const float* lq2 = (const float*)d_in[7];
  const float* lk2 = (const float*)d_in[8];
  float* out = (float*)d_out;

  char* ws = (char*)d_ws;
  size_t off = 0;
  auto alloc = [&](size_t bytes) -> char* {
    char* p = ws + off;
    off += (bytes + 255) & ~(size_t)255;
    return p;
  };
  bf16_t* xb  = (bf16_t*)alloc((size_t)4096 * 1024 * 2);
  bf16_t* Wqt = (bf16_t*)alloc((size_t)2048 * 1024 * 2);
  bf16_t* Wkt = (bf16_t*)alloc((size_t)2048 * 1024 * 2);
  bf16_t* Wvt = (bf16_t*)alloc((size_t)2048 * 1024 * 2);
  bf16_t* Wot = (bf16_t*)alloc((size_t)1024 * 1024 * 2);
  bf16_t* Qb  = (bf16_t*)alloc((size_t)4096 * 2048 * 2);
  bf16_t* Kb  = (bf16_t*)alloc((size_t)4096 * 2048 * 2);
  bf16_t* Vtg = (bf16_t*)alloc((size_t)4096 * 2048 * 2);
  bf16_t* Ob  = (bf16_t*)alloc((size_t)4096 * 1024 * 2);
  float*  lamp = (float*)alloc(256);

  lam_kernel<<<1, 64, 0, stream>>>(lq1, lk1, lq2, lk2, lamp);
  cvt_x_kernel<<<4096, 256, 0, stream>>>(x, xb);
  transpose_cvt<<<dim3(64, 32), dim3(32, 8), 0, stream>>>(Wq, Wqt, 1024, 2048);
  transpose_cvt<<<dim3(64, 32), dim3(32, 8), 0, stream>>>(Wk, Wkt, 1024, 2048);
  transpose_cvt<<<dim3(64, 32), dim3(32, 8), 0, stream>>>(Wv, Wvt, 1024, 2048);
  transpose_cvt<<<dim3(32, 32), dim3(32, 8), 0, stream>>>(Wo, Wot, 1024, 1024);
  gemm_qkv<<<dim3(16, 32, 3), 256, 0, stream>>>(xb, Wqt, Wkt, Wvt, Qb, Kb, Vtg);
  attn_kernel<<<256, 512, 0, stream>>>(Qb, Kb, Vtg, Ob, lamp);
  gemm_out<<<dim3(8, 32), 256, 0, stream>>>(Ob, Wot, out);
}